// Round 5
// baseline (350.871 us; speedup 1.0000x reference)
//
#include <hip/hip_runtime.h>

typedef unsigned int u32;
typedef unsigned long long u64;

#define B 8
#define H 1024
#define W 1024
#define TOPK 4096
#define HSTRIDE 8200           // 8193 buckets, padded
#define CANDCAP 131072         // per image
#define GCAP 8192              // gathered per image
#define LBUFW 512              // per-wave candidate buffer (rigorous max 495 for 44x32 strip)

#define MAX5R(A, j) fmaxf(fmaxf(fmaxf(A[j], A[(j)+1]), fmaxf(A[(j)+2], A[(j)+3])), A[(j)+4])
#define OR5(A, j) (A[j] | A[(j)+1] | A[(j)+2] | A[(j)+3] | A[(j)+4])

__device__ __forceinline__ u32 val_bucket(u32 vb) {
    if (vb < 0x3F000000u) return 0u;
    u32 b = ((vb - 0x3F000000u) >> 10) + 1u;
    return b > 8192u ? 8192u : b;
}

__device__ __forceinline__ float max5(float a, float b, float c, float d, float e) {
    return fmaxf(fmaxf(fmaxf(a, b), fmaxf(c, d)), e);
}

__device__ __forceinline__ u64 xdilate(u64 m) {
    return m | (m << 1) | (m >> 1) | (m << 2) | (m >> 2);
}

__device__ __forceinline__ float bsel(u64 mask, u64 lanebit, float v) {
    return (mask & lanebit) ? 0.0f : v;
}

// ---------------- streaming register-pipeline NMS ----------------
// One wave per 44-col x 32-row output strip; streams 52 input rows.
// Masks are wave-uniform u64 ballots; suppressed-value neighborhoods are
// rebuilt from RAW shuffled rows + scalar-shifted ballot masks, so the
// ds_bpermute latency is off the ballot->SALU->ballot critical path.

__global__ __launch_bounds__(256) void k_nms(const float* __restrict__ S_,
                                             u64* __restrict__ cand,
                                             u32* __restrict__ cnt,
                                             u32* __restrict__ hist) {
    __shared__ u64 lbuf[4][LBUFW];

    int lane = threadIdx.x & 63;
    int wslot = threadIdx.x >> 6;
    int sx = blockIdx.x * 4 + wslot;      // 0..23  (24*44 = 1056 >= 1024)
    int sy = blockIdx.y;                  // 0..31
    int img = blockIdx.z;
    int gx0 = sx * 44 - 10;
    int gy0 = sy * 32;
    int gx = gx0 + lane;
    bool lxok = (unsigned)gx < (unsigned)W;
    u64 lanebit = 1ull << lane;
    const float* Sb = S_ + ((size_t)img << 20);

    u64 validx = __ballot(lxok);
    u64 emask = __ballot(lane >= 10 && lane <= 53 && gx >= 2 && gx <= W - 3);

    // rolling windows (same offsets as verified round-4 pipeline):
    // S[k]=s(y0-10+k); R0[k]=r0(y0-4+k); M0[k]=m0(y0-6+k); SP1[k]=sp1(y0-6+k);
    // R1[k]=hss1(y0-8+k); M1[k]=m1(y0-10+k); SP2[k]=sp2(y0-10+k); R2[k]=hss2(y0-12+k)
    float S[14], R0[8], R1[8], R2[8];
    u64 M0[8], M1[8], SP1[6], SP2[6];
#pragma unroll
    for (int k = 0; k < 14; ++k) S[k] = -1.0f;
#pragma unroll
    for (int k = 0; k < 8; ++k) { R0[k] = -1e30f; R1[k] = -1e30f; R2[k] = -1e30f; M0[k] = 0; M1[k] = 0; }
#pragma unroll
    for (int k = 0; k < 6; ++k) { SP1[k] = 0; SP2[k] = 0; }

    u32 wbase = 0;
    int y0 = gy0 - 10;

    for (int cy = 0; cy < 13; ++cy, y0 += 4) {
#pragma unroll
        for (int j = 0; j < 4; ++j) {
            int gy = y0 + j;
            float v = -1.0f;
            if ((unsigned)gy < (unsigned)H && lxok) v = Sb[(gy << 10) + gx];
            S[10 + j] = v;
        }
#pragma unroll
        for (int j = 0; j < 4; ++j) {
            // raw-row shuffles (independent of ballot chain; issue early)
            float fr = S[10 + j];
            float f_m1 = __shfl_up(fr, 1), f_m2 = __shfl_up(fr, 2);
            float f_p1 = __shfl_down(fr, 1), f_p2 = __shfl_down(fr, 2);
            float ar = S[j + 6];
            float a_m1 = __shfl_up(ar, 1), a_m2 = __shfl_up(ar, 2);
            float a_p1 = __shfl_down(ar, 1), a_p2 = __shfl_down(ar, 2);
            float br = S[j + 2];
            float b_m1 = __shfl_up(br, 1), b_m2 = __shfl_up(br, 2);
            float b_p1 = __shfl_down(br, 1), b_p2 = __shfl_down(br, 2);

            // P0: r0(y), m0(y-2)
            R0[4 + j] = max5(f_m2, f_m1, fr, f_p1, f_p2);
            float c0 = MAX5R(R0, j);
            u64 m0 = __ballot(S[j + 8] == c0) & validx;
            M0[4 + j] = m0;

            // P1: sp1(y-4) = dilate5x5(m0 rows)
            u64 sp1 = xdilate(OR5(M0, j));
            SP1[2 + j] = sp1;

            // P2: hmax of ss1 at row y-4 from raw neighbors + shifted mask
            float h1 = max5(bsel(sp1 << 2, lanebit, a_m2), bsel(sp1 << 1, lanebit, a_m1),
                            bsel(sp1, lanebit, ar),
                            bsel(sp1 >> 1, lanebit, a_p1), bsel(sp1 >> 2, lanebit, a_p2));
            R1[4 + j] = h1;
            float c1 = MAX5R(R1, j);
            float ss1b = bsel(SP1[j], lanebit, S[j + 4]);
            u64 new1 = __ballot(ss1b == c1) & validx;
            u64 m1 = M0[j] | (new1 & ~SP1[j]);
            M1[4 + j] = m1;

            // P3: sp2(y-8)
            u64 sp2 = xdilate(OR5(M1, j));
            SP2[2 + j] = sp2;

            // P4: hmax of ss2 at row y-8
            float h2 = max5(bsel(sp2 << 2, lanebit, b_m2), bsel(sp2 << 1, lanebit, b_m1),
                            bsel(sp2, lanebit, br),
                            bsel(sp2 >> 1, lanebit, b_p1), bsel(sp2 >> 2, lanebit, b_p2));
            R2[4 + j] = h2;

            if (cy >= 5) {
                float c2 = MAX5R(R2, j);
                float ss2b = bsel(SP2[j], lanebit, S[j]);
                u64 new2 = __ballot(ss2b == c2) & validx;
                u64 m2 = M1[j] | (new2 & ~SP2[j]);
                int gy_out = y0 + j - 10;
                if (gy_out >= 2 && gy_out <= H - 3) {
                    float val = (m2 & lanebit) ? S[j] : 0.0f;
                    u64 bm = __ballot(val > 0.0f) & emask;
                    if (bm) {
                        u32 cw = (u32)__popcll(bm);
                        u32 prefix = (u32)__popcll(bm & (lanebit - 1ull));
                        if ((bm & lanebit) && (wbase + prefix) < LBUFW) {
                            u64 key = (((u64)__float_as_uint(val)) << 32) |
                                      (u32)(~(u32)((gy_out << 10) + gx));
                            lbuf[wslot][wbase + prefix] = key;
                        }
                        wbase += cw;
                    }
                }
            }
        }
        // shift windows by 4
#pragma unroll
        for (int k = 0; k < 10; ++k) S[k] = S[k + 4];
#pragma unroll
        for (int k = 0; k < 4; ++k) {
            R0[k] = R0[k + 4]; R1[k] = R1[k + 4]; R2[k] = R2[k + 4];
            M0[k] = M0[k + 4]; M1[k] = M1[k + 4];
        }
#pragma unroll
        for (int k = 0; k < 2; ++k) { SP1[k] = SP1[k + 4]; SP2[k] = SP2[k + 4]; }
    }

    // flush: one global atomic per wave, then burst copy + histogram
    u32 total = wbase > LBUFW ? LBUFW : wbase;
    u32 gbase = 0;
    if (lane == 0) gbase = atomicAdd(&cnt[img], total);
    gbase = (u32)__shfl((int)gbase, 0, 64);
    u64* dst = cand + ((size_t)img << 17);
    u32* hb = hist + (u32)img * HSTRIDE;
    for (u32 i = lane; i < total; i += 64) {
        u64 key = lbuf[wslot][i];
        atomicAdd(&hb[val_bucket((u32)(key >> 32))], 1u);
        dst[gbase + i] = key;
    }
}

// ---------------- threshold bucket ----------------

__global__ __launch_bounds__(1024) void k_thresh(const u32* __restrict__ hist,
                                                 u32* __restrict__ Bstar) {
    __shared__ u32 sc[1024];
    __shared__ u32 part[1024];
    int img = blockIdx.x;
    int t = threadIdx.x;
    const u32* h = hist + (u32)img * HSTRIDE;
    u32 loc[8];
    u32 psum = 0;
#pragma unroll
    for (int i = 0; i < 8; ++i) { loc[i] = h[8192 - (t * 8 + i)]; psum += loc[i]; }
    part[t] = psum;
    sc[t] = psum;
    __syncthreads();
    for (int off = 1; off < 1024; off <<= 1) {
        u32 add = (t >= off) ? sc[t - off] : 0;
        __syncthreads();
        sc[t] += add;
        __syncthreads();
    }
    u32 total = sc[1023];
    u32 cumBefore = sc[t] - part[t];
    if (total < TOPK) {
        if (t == 0) Bstar[img] = 0;
    } else if (cumBefore < TOPK && sc[t] >= TOPK) {
        u32 cum = cumBefore;
#pragma unroll
        for (int i = 0; i < 8; ++i) {
            if (cum < TOPK && cum + loc[i] >= TOPK) Bstar[img] = (u32)(8192 - (t * 8 + i));
            cum += loc[i];
        }
    }
}

// ---------------- gather (parallel, ballot-aggregated atomics) ----------------

__global__ void k_gather(const u64* __restrict__ cand,
                         const u32* __restrict__ cnt,
                         const u32* __restrict__ Bstar,
                         u64* __restrict__ gath,
                         u32* __restrict__ gcnt) {
    int img = blockIdx.y;
    u32 n = cnt[img];
    u32 Bs = Bstar[img];
    const u64* c = cand + ((size_t)img << 17);
    u32 lane = threadIdx.x & 63;
    u32 npad = (n + 8191u) & ~8191u;
    for (u32 i = blockIdx.x * 256 + threadIdx.x; i < npad; i += 8192) {
        bool pass = false;
        u64 key = 0;
        if (i < n) {
            key = c[i];
            pass = val_bucket((u32)(key >> 32)) >= Bs;
        }
        u64 bm = __ballot(pass);
        if (bm) {
            u32 cw = (u32)__popcll(bm);
            int ldr = __ffsll((unsigned long long)bm) - 1;
            u32 wb = 0;
            if ((int)lane == ldr) wb = atomicAdd(&gcnt[img], cw);
            wb = (u32)__shfl((int)wb, ldr, 64);
            u32 before = (u32)__popcll(bm & ((1ull << lane) - 1ull));
            if (pass && wb + before < GCAP)
                gath[((size_t)img << 13) + wb + before] = key;
        }
    }
}

// ---------------- fused: exact rank + softmax patch + dispersity + bilinear ----------------

__global__ __launch_bounds__(256) void k_rankfinal(const u64* __restrict__ gath,
                                                   const u32* __restrict__ gcnt,
                                                   const float* __restrict__ S,
                                                   float* __restrict__ out) {
    __shared__ u64 a[GCAP];   // 64 KB
    int img = blockIdx.y;
    int t = threadIdx.x;
    u32 n = gcnt[img];
    if (n > GCAP) n = GCAP;
    const u64* src = gath + ((size_t)img << 13);
    for (u32 j = t; j < n; j += 256) a[j] = src[j];
    __syncthreads();

    u32 i = blockIdx.x * 256 + t;
    u32 r = TOPK;
    u64 key = 0;
    if (i < n) {
        key = a[i];
        r = 0;
        u32 j = 0;
        for (; j + 8 <= n; j += 8) {
            r += (a[j] > key)     + (a[j + 1] > key) + (a[j + 2] > key) + (a[j + 3] > key);
            r += (a[j + 4] > key) + (a[j + 5] > key) + (a[j + 6] > key) + (a[j + 7] > key);
        }
        for (; j < n; ++j) r += (a[j] > key);
    }
    if (r >= TOPK) return;

    u32 rem = ~(u32)(key & 0xFFFFFFFFull);
    int row = (int)(rem >> 10);
    int col = (int)(rem & (W - 1));
    const float* Sb = S + ((size_t)img << 20);

    float p[25];
    float mx = -1e30f;
#pragma unroll
    for (int a2 = 0; a2 < 5; ++a2) {
        int y = row + a2 - 2;
#pragma unroll
        for (int c2 = 0; c2 < 5; ++c2) {
            int x = col + c2 - 2;
            float v = (y >= 0 && y < H && x >= 0 && x < W) ? Sb[(y << 10) + x] : 0.0f;
            p[a2 * 5 + c2] = v;
            mx = fmaxf(mx, v);
        }
    }
    float sum = 0.0f, sx = 0.0f, sy = 0.0f;
#pragma unroll
    for (int a2 = 0; a2 < 5; ++a2) {
#pragma unroll
        for (int c2 = 0; c2 < 5; ++c2) {
            float e = expf((p[a2 * 5 + c2] - mx) / 0.1f);
            p[a2 * 5 + c2] = e;
            sum += e;
            sx += e * (float)(c2 - 2);
            sy += e * (float)(a2 - 2);
        }
    }
    float rx = sx / sum, ry = sy / sum;
    float sd = 0.0f;
#pragma unroll
    for (int a2 = 0; a2 < 5; ++a2) {
#pragma unroll
        for (int c2 = 0; c2 < 5; ++c2) {
            float dxx = ((float)(c2 - 2) - rx) * 0.5f;
            float dyy = ((float)(a2 - 2) - ry) * 0.5f;
            sd += p[a2 * 5 + c2] * (dxx * dxx + dyy * dyy);
        }
    }
    float disp = sd / sum;
    float kx = ((float)col + rx) / (float)(W - 1) * 2.0f - 1.0f;
    float ky = ((float)row + ry) / (float)(H - 1) * 2.0f - 1.0f;

    float px = (kx + 1.0f) * 0.5f * (float)(W - 1);
    float py = (ky + 1.0f) * 0.5f * (float)(H - 1);
    float x0 = floorf(px), y0 = floorf(py);
    float wx1 = px - x0, wx0 = 1.0f - wx1;
    float wy1 = py - y0, wy0 = 1.0f - wy1;

    float gg[4];
    float xs[4] = {x0, x0 + 1.0f, x0, x0 + 1.0f};
    float ys[4] = {y0, y0, y0 + 1.0f, y0 + 1.0f};
#pragma unroll
    for (int q = 0; q < 4; ++q) {
        int xi = (int)xs[q]; xi = xi < 0 ? 0 : (xi > W - 1 ? W - 1 : xi);
        int yi = (int)ys[q]; yi = yi < 0 ? 0 : (yi > H - 1 ? H - 1 : yi);
        bool valid = (xs[q] >= 0.0f) && (xs[q] <= (float)(W - 1)) &&
                     (ys[q] >= 0.0f) && (ys[q] <= (float)(H - 1));
        gg[q] = valid ? Sb[(yi << 10) + xi] : 0.0f;
    }
    float score = wy0 * wx0 * gg[0] + wy0 * wx1 * gg[1] + wy1 * wx0 * gg[2] + wy1 * wx1 * gg[3];

    u32 slot = ((u32)img << 12) + r;
    out[(size_t)slot * 2]     = kx;
    out[(size_t)slot * 2 + 1] = ky;
    out[B * TOPK * 2 + slot]            = disp;
    out[B * TOPK * 2 + B * TOPK + slot] = score;
}

// ---------------- launch ----------------

extern "C" void kernel_launch(void* const* d_in, const int* in_sizes, int n_in,
                              void* d_out, int out_size, void* d_ws, size_t ws_size,
                              hipStream_t stream) {
    const float* S = (const float*)d_in[0];
    float* out = (float*)d_out;

    char* w = (char*)d_ws;
    u64* cand = (u64*)w;        w += (size_t)B * CANDCAP * 8;
    u64* gath = (u64*)w;        w += (size_t)B * GCAP * 8;
    u32* Bstar = (u32*)w;       w += B * 4;
    u32* hist = (u32*)w;        w += (size_t)B * HSTRIDE * 4;
    u32* cnt = (u32*)w;         w += B * 4;
    u32* gcnt = (u32*)w;        w += B * 4;

    // zero hist + cnt + gcnt (contiguous)
    hipMemsetAsync(hist, 0, (size_t)B * HSTRIDE * 4 + 2 * B * 4, stream);

    k_nms<<<dim3(6, 32, B), 256, 0, stream>>>(S, cand, cnt, hist);
    k_thresh<<<B, 1024, 0, stream>>>(hist, Bstar);
    k_gather<<<dim3(32, B), 256, 0, stream>>>(cand, cnt, Bstar, gath, gcnt);
    k_rankfinal<<<dim3(32, B), 256, 0, stream>>>(gath, gcnt, S, out);
}

// Round 6
// 298.053 us; speedup vs baseline: 1.1772x; 1.1772x over previous
//
#include <hip/hip_runtime.h>

typedef unsigned int u32;
typedef unsigned long long u64;

#define B 8
#define H 1024
#define W 1024
#define TOPK 4096
#define CANDCAP 131072         // per image
#define GCAP 8192              // gathered per image
#define LBUFW 1024             // per-wave cap (rigorous max 990 for 44x64 strip)

#define MAX5R(A, j) fmaxf(fmaxf(fmaxf(A[j], A[(j)+1]), fmaxf(A[(j)+2], A[(j)+3])), A[(j)+4])
#define OR5(A, j) (A[j] | A[(j)+1] | A[(j)+2] | A[(j)+3] | A[(j)+4])

__device__ __forceinline__ u32 val_bucket(u32 vb) {
    if (vb < 0x3F000000u) return 0u;
    u32 b = ((vb - 0x3F000000u) >> 10) + 1u;
    return b > 8192u ? 8192u : b;
}

__device__ __forceinline__ float max5(float a, float b, float c, float d, float e) {
    return fmaxf(fmaxf(fmaxf(a, b), fmaxf(c, d)), e);
}

__device__ __forceinline__ u64 xdilate(u64 m) {
    return m | (m << 1) | (m >> 1) | (m << 2) | (m >> 2);
}

__device__ __forceinline__ float bsel(u64 mask, u64 lanebit, float v) {
    return (mask & lanebit) ? 0.0f : v;
}

// ---------------- streaming register-pipeline NMS ----------------
// One wave per 44-col x 64-row output strip; streams 84 input rows.
// launch_bounds(256,4): <=128 VGPR so the 4 unrolled row-chains stay live
// and interleave (r5's VGPR=32 serialized them -> 31% VALUBusy).

__global__ __launch_bounds__(256, 4) void k_nms(const float* __restrict__ S_,
                                                u64* __restrict__ cand,
                                                u32* __restrict__ cnt) {
    __shared__ u64 lbuf[4][LBUFW];

    int lane = threadIdx.x & 63;
    int wslot = threadIdx.x >> 6;
    int sx = blockIdx.x * 4 + wslot;      // 0..23  (24*44 = 1056 >= 1024)
    int sy = blockIdx.y;                  // 0..15  (64-row strips)
    int img = blockIdx.z;
    int gx0 = sx * 44 - 10;
    int gy0 = sy * 64;
    int gx = gx0 + lane;
    bool lxok = (unsigned)gx < (unsigned)W;
    u64 lanebit = 1ull << lane;
    const float* Sb = S_ + ((size_t)img << 20);

    u64 validx = __ballot(lxok);
    u64 emask = __ballot(lane >= 10 && lane <= 53 && gx >= 2 && gx <= W - 3);

    // rolling windows: S[k]=s(y0-10+k); R0[k]=r0(y0-4+k); M0[k]=m0(y0-6+k);
    // SP1[k]=sp1(y0-6+k); R1[k]=hss1(y0-8+k); M1[k]=m1(y0-10+k);
    // SP2[k]=sp2(y0-10+k); R2[k]=hss2(y0-12+k)
    float S[14], R0[8], R1[8], R2[8], nxt[4];
    u64 M0[8], M1[8], SP1[6], SP2[6];
#pragma unroll
    for (int k = 0; k < 14; ++k) S[k] = -1.0f;
#pragma unroll
    for (int k = 0; k < 8; ++k) { R0[k] = -1e30f; R1[k] = -1e30f; R2[k] = -1e30f; M0[k] = 0; M1[k] = 0; }
#pragma unroll
    for (int k = 0; k < 6; ++k) { SP1[k] = 0; SP2[k] = 0; }

    u32 wbase = 0;
    int y0 = gy0 - 10;

    // preload first 4 rows
#pragma unroll
    for (int j = 0; j < 4; ++j) {
        int gy = y0 + j;
        nxt[j] = ((unsigned)gy < (unsigned)H && lxok) ? Sb[(gy << 10) + gx] : -1.0f;
    }

    for (int cy = 0; cy < 21; ++cy, y0 += 4) {
#pragma unroll
        for (int j = 0; j < 4; ++j) S[10 + j] = nxt[j];
        // issue next block's loads early (latency hidden under compute)
        if (cy < 20) {
#pragma unroll
            for (int j = 0; j < 4; ++j) {
                int gy = y0 + 4 + j;
                nxt[j] = ((unsigned)gy < (unsigned)H && lxok) ? Sb[(gy << 10) + gx] : -1.0f;
            }
        }
#pragma unroll
        for (int j = 0; j < 4; ++j) {
            // raw-row shuffles (independent of ballot chain)
            float fr = S[10 + j];
            float f_m1 = __shfl_up(fr, 1), f_m2 = __shfl_up(fr, 2);
            float f_p1 = __shfl_down(fr, 1), f_p2 = __shfl_down(fr, 2);
            float ar = S[j + 6];
            float a_m1 = __shfl_up(ar, 1), a_m2 = __shfl_up(ar, 2);
            float a_p1 = __shfl_down(ar, 1), a_p2 = __shfl_down(ar, 2);
            float br = S[j + 2];
            float b_m1 = __shfl_up(br, 1), b_m2 = __shfl_up(br, 2);
            float b_p1 = __shfl_down(br, 1), b_p2 = __shfl_down(br, 2);

            // P0: r0(y), m0(y-2)
            R0[4 + j] = max5(f_m2, f_m1, fr, f_p1, f_p2);
            float c0 = MAX5R(R0, j);
            u64 m0 = __ballot(S[j + 8] == c0) & validx;
            M0[4 + j] = m0;

            // P1: sp1(y-4) = dilate5x5(m0 rows)
            u64 sp1 = xdilate(OR5(M0, j));
            SP1[2 + j] = sp1;

            // P2: hmax of ss1 at row y-4 from raw neighbors + shifted mask
            float h1 = max5(bsel(sp1 << 2, lanebit, a_m2), bsel(sp1 << 1, lanebit, a_m1),
                            bsel(sp1, lanebit, ar),
                            bsel(sp1 >> 1, lanebit, a_p1), bsel(sp1 >> 2, lanebit, a_p2));
            R1[4 + j] = h1;
            float c1 = MAX5R(R1, j);
            float ss1b = bsel(SP1[j], lanebit, S[j + 4]);
            u64 new1 = __ballot(ss1b == c1) & validx;
            u64 m1 = M0[j] | (new1 & ~SP1[j]);
            M1[4 + j] = m1;

            // P3: sp2(y-8)
            u64 sp2 = xdilate(OR5(M1, j));
            SP2[2 + j] = sp2;

            // P4: hmax of ss2 at row y-8
            float h2 = max5(bsel(sp2 << 2, lanebit, b_m2), bsel(sp2 << 1, lanebit, b_m1),
                            bsel(sp2, lanebit, br),
                            bsel(sp2 >> 1, lanebit, b_p1), bsel(sp2 >> 2, lanebit, b_p2));
            R2[4 + j] = h2;

            if (cy >= 5) {
                float c2 = MAX5R(R2, j);
                float ss2b = bsel(SP2[j], lanebit, S[j]);
                u64 new2 = __ballot(ss2b == c2) & validx;
                u64 m2 = M1[j] | (new2 & ~SP2[j]);
                int gy_out = y0 + j - 10;
                if (gy_out >= 2 && gy_out <= H - 3) {
                    float val = (m2 & lanebit) ? S[j] : 0.0f;
                    u64 bm = __ballot(val > 0.0f) & emask;
                    if (bm) {
                        u32 cw = (u32)__popcll(bm);
                        u32 prefix = (u32)__popcll(bm & (lanebit - 1ull));
                        if ((bm & lanebit) && (wbase + prefix) < LBUFW) {
                            u64 key = (((u64)__float_as_uint(val)) << 32) |
                                      (u32)(~(u32)((gy_out << 10) + gx));
                            lbuf[wslot][wbase + prefix] = key;
                        }
                        wbase += cw;
                    }
                }
            }
        }
        // shift windows by 4
#pragma unroll
        for (int k = 0; k < 10; ++k) S[k] = S[k + 4];
#pragma unroll
        for (int k = 0; k < 4; ++k) {
            R0[k] = R0[k + 4]; R1[k] = R1[k + 4]; R2[k] = R2[k + 4];
            M0[k] = M0[k + 4]; M1[k] = M1[k + 4];
        }
#pragma unroll
        for (int k = 0; k < 2; ++k) { SP1[k] = SP1[k + 4]; SP2[k] = SP2[k + 4]; }
    }

    // flush: one global atomic per wave, contiguous stores (no hist atomics)
    u32 total = wbase > LBUFW ? LBUFW : wbase;
    u32 gbase = 0;
    if (lane == 0) gbase = atomicAdd(&cnt[img], total);
    gbase = (u32)__shfl((int)gbase, 0, 64);
    u64* dst = cand + ((size_t)img << 17);
    for (u32 i = lane; i < total; i += 64)
        dst[gbase + i] = lbuf[wslot][i];
}

// ---------------- LDS histogram + threshold bucket (1 block / image) ----------------

__global__ __launch_bounds__(1024) void k_thresh(const u64* __restrict__ cand,
                                                 const u32* __restrict__ cnt,
                                                 u32* __restrict__ Bstar) {
    __shared__ u32 h[8193];          // 32.8 KB
    __shared__ u32 wpart[16];
    __shared__ u32 woff[16];
    int img = blockIdx.x;
    int t = threadIdx.x;
    int lane = t & 63, wid = t >> 6;

    for (int i = t; i < 8193; i += 1024) h[i] = 0;
    __syncthreads();

    u32 n = cnt[img];
    const u64* c = cand + ((size_t)img << 17);
    for (u32 i = t; i < n; i += 1024)
        atomicAdd(&h[val_bucket((u32)(c[i] >> 32))], 1u);
    __syncthreads();

    // thread t owns buckets hi..hi-7 (descending value order as t grows)
    int hi = 8192 - 8 * t;
    u32 loc[8];
    u32 psum = 0;
#pragma unroll
    for (int i = 0; i < 8; ++i) { loc[i] = h[hi - i]; psum += loc[i]; }

    // wave-inclusive scan of psum, then block offsets
    u32 incl = psum;
#pragma unroll
    for (int d = 1; d < 64; d <<= 1) {
        u32 v = (u32)__shfl_up((int)incl, d);
        if (lane >= d) incl += v;
    }
    if (lane == 63) wpart[wid] = incl;
    __syncthreads();
    if (t == 0) {
        u32 acc = 0;
        for (int w2 = 0; w2 < 16; ++w2) { woff[w2] = acc; acc += wpart[w2]; }
    }
    __syncthreads();
    u32 total = woff[15] + wpart[15];
    u32 excl = incl - psum + woff[wid];

    if (total < TOPK) {
        if (t == 0) Bstar[img] = 0;
    } else if (excl < TOPK && excl + psum >= TOPK) {
        u32 cum = excl;
#pragma unroll
        for (int i = 0; i < 8; ++i) {
            cum += loc[i];
            if (cum >= TOPK) { Bstar[img] = (u32)(hi - i); break; }
        }
    }
}

// ---------------- gather (parallel, ballot-aggregated atomics) ----------------

__global__ void k_gather(const u64* __restrict__ cand,
                         const u32* __restrict__ cnt,
                         const u32* __restrict__ Bstar,
                         u64* __restrict__ gath,
                         u32* __restrict__ gcnt) {
    int img = blockIdx.y;
    u32 n = cnt[img];
    u32 Bs = Bstar[img];
    const u64* c = cand + ((size_t)img << 17);
    u32 lane = threadIdx.x & 63;
    u32 npad = (n + 8191u) & ~8191u;
    for (u32 i = blockIdx.x * 256 + threadIdx.x; i < npad; i += 8192) {
        bool pass = false;
        u64 key = 0;
        if (i < n) {
            key = c[i];
            pass = val_bucket((u32)(key >> 32)) >= Bs;
        }
        u64 bm = __ballot(pass);
        if (bm) {
            u32 cw = (u32)__popcll(bm);
            int ldr = __ffsll((unsigned long long)bm) - 1;
            u32 wb = 0;
            if ((int)lane == ldr) wb = atomicAdd(&gcnt[img], cw);
            wb = (u32)__shfl((int)wb, ldr, 64);
            u32 before = (u32)__popcll(bm & ((1ull << lane) - 1ull));
            if (pass && wb + before < GCAP)
                gath[((size_t)img << 13) + wb + before] = key;
        }
    }
}

// ---------------- fused: exact rank + softmax patch + dispersity + bilinear ----------------

__global__ __launch_bounds__(256) void k_rankfinal(const u64* __restrict__ gath,
                                                   const u32* __restrict__ gcnt,
                                                   const float* __restrict__ S,
                                                   float* __restrict__ out) {
    __shared__ u64 a[GCAP];   // 64 KB
    int img = blockIdx.y;
    int t = threadIdx.x;
    u32 n = gcnt[img];
    if (n > GCAP) n = GCAP;
    if (blockIdx.x * 256 >= n) return;     // uniform early-exit, skip LDS load
    const u64* src = gath + ((size_t)img << 13);
    for (u32 j = t; j < n; j += 256) a[j] = src[j];
    __syncthreads();

    u32 i = blockIdx.x * 256 + t;
    u32 r = TOPK;
    u64 key = 0;
    if (i < n) {
        key = a[i];
        r = 0;
        u32 j = 0;
        for (; j + 8 <= n; j += 8) {
            r += (a[j] > key)     + (a[j + 1] > key) + (a[j + 2] > key) + (a[j + 3] > key);
            r += (a[j + 4] > key) + (a[j + 5] > key) + (a[j + 6] > key) + (a[j + 7] > key);
        }
        for (; j < n; ++j) r += (a[j] > key);
    }
    if (r >= TOPK) return;

    u32 rem = ~(u32)(key & 0xFFFFFFFFull);
    int row = (int)(rem >> 10);
    int col = (int)(rem & (W - 1));
    const float* Sb = S + ((size_t)img << 20);

    float p[25];
    float mx = -1e30f;
#pragma unroll
    for (int a2 = 0; a2 < 5; ++a2) {
        int y = row + a2 - 2;
#pragma unroll
        for (int c2 = 0; c2 < 5; ++c2) {
            int x = col + c2 - 2;
            float v = (y >= 0 && y < H && x >= 0 && x < W) ? Sb[(y << 10) + x] : 0.0f;
            p[a2 * 5 + c2] = v;
            mx = fmaxf(mx, v);
        }
    }
    float sum = 0.0f, sx = 0.0f, sy = 0.0f;
#pragma unroll
    for (int a2 = 0; a2 < 5; ++a2) {
#pragma unroll
        for (int c2 = 0; c2 < 5; ++c2) {
            float e = expf((p[a2 * 5 + c2] - mx) / 0.1f);
            p[a2 * 5 + c2] = e;
            sum += e;
            sx += e * (float)(c2 - 2);
            sy += e * (float)(a2 - 2);
        }
    }
    float rx = sx / sum, ry = sy / sum;
    float sd = 0.0f;
#pragma unroll
    for (int a2 = 0; a2 < 5; ++a2) {
#pragma unroll
        for (int c2 = 0; c2 < 5; ++c2) {
            float dxx = ((float)(c2 - 2) - rx) * 0.5f;
            float dyy = ((float)(a2 - 2) - ry) * 0.5f;
            sd += p[a2 * 5 + c2] * (dxx * dxx + dyy * dyy);
        }
    }
    float disp = sd / sum;
    float kx = ((float)col + rx) / (float)(W - 1) * 2.0f - 1.0f;
    float ky = ((float)row + ry) / (float)(H - 1) * 2.0f - 1.0f;

    float px = (kx + 1.0f) * 0.5f * (float)(W - 1);
    float py = (ky + 1.0f) * 0.5f * (float)(H - 1);
    float x0 = floorf(px), y0 = floorf(py);
    float wx1 = px - x0, wx0 = 1.0f - wx1;
    float wy1 = py - y0, wy0 = 1.0f - wy1;

    float gg[4];
    float xs[4] = {x0, x0 + 1.0f, x0, x0 + 1.0f};
    float ys[4] = {y0, y0, y0 + 1.0f, y0 + 1.0f};
#pragma unroll
    for (int q = 0; q < 4; ++q) {
        int xi = (int)xs[q]; xi = xi < 0 ? 0 : (xi > W - 1 ? W - 1 : xi);
        int yi = (int)ys[q]; yi = yi < 0 ? 0 : (yi > H - 1 ? H - 1 : yi);
        bool valid = (xs[q] >= 0.0f) && (xs[q] <= (float)(W - 1)) &&
                     (ys[q] >= 0.0f) && (ys[q] <= (float)(H - 1));
        gg[q] = valid ? Sb[(yi << 10) + xi] : 0.0f;
    }
    float score = wy0 * wx0 * gg[0] + wy0 * wx1 * gg[1] + wy1 * wx0 * gg[2] + wy1 * wx1 * gg[3];

    u32 slot = ((u32)img << 12) + r;
    out[(size_t)slot * 2]     = kx;
    out[(size_t)slot * 2 + 1] = ky;
    out[B * TOPK * 2 + slot]            = disp;
    out[B * TOPK * 2 + B * TOPK + slot] = score;
}

// ---------------- launch ----------------

extern "C" void kernel_launch(void* const* d_in, const int* in_sizes, int n_in,
                              void* d_out, int out_size, void* d_ws, size_t ws_size,
                              hipStream_t stream) {
    const float* S = (const float*)d_in[0];
    float* out = (float*)d_out;

    char* w = (char*)d_ws;
    u64* cand = (u64*)w;        w += (size_t)B * CANDCAP * 8;
    u64* gath = (u64*)w;        w += (size_t)B * GCAP * 8;
    u32* Bstar = (u32*)w;       w += B * 4;
    u32* cnt = (u32*)w;         w += B * 4;
    u32* gcnt = (u32*)w;        w += B * 4;

    // zero cnt + gcnt (contiguous, 64 B)
    hipMemsetAsync(cnt, 0, 2 * B * 4, stream);

    k_nms<<<dim3(6, 16, B), 256, 0, stream>>>(S, cand, cnt);
    k_thresh<<<B, 1024, 0, stream>>>(cand, cnt, Bstar);
    k_gather<<<dim3(32, B), 256, 0, stream>>>(cand, cnt, Bstar, gath, gcnt);
    k_rankfinal<<<dim3(32, B), 256, 0, stream>>>(gath, gcnt, S, out);
}

// Round 7
// 160.700 us; speedup vs baseline: 2.1834x; 1.8547x over previous
//
#include <hip/hip_runtime.h>

typedef unsigned int u32;
typedef unsigned long long u64;

#define B 8
#define H 1024
#define W 1024
#define TOPK 4096
#define CANDCAP 131072         // per image
#define GCAP 8192              // gathered per image
#define LBUFW 1024             // per-wave cap (rigorous max 990 for 44x64 strip)
#define CSTR 32                // cnt/gcnt stride in u32 (128 B -> no cross-image line bounce)

#define MAX5R(A, j) fmaxf(fmaxf(fmaxf(A[j], A[(j)+1]), fmaxf(A[(j)+2], A[(j)+3])), A[(j)+4])
#define OR5(A, j) (A[j] | A[(j)+1] | A[(j)+2] | A[(j)+3] | A[(j)+4])

__device__ __forceinline__ u32 val_bucket(u32 vb) {
    if (vb < 0x3F000000u) return 0u;
    u32 b = ((vb - 0x3F000000u) >> 10) + 1u;
    return b > 8192u ? 8192u : b;
}

__device__ __forceinline__ float max5(float a, float b, float c, float d, float e) {
    return fmaxf(fmaxf(fmaxf(a, b), fmaxf(c, d)), e);
}

__device__ __forceinline__ u64 xdilate(u64 m) {
    return m | (m << 1) | (m >> 1) | (m << 2) | (m >> 2);
}

__device__ __forceinline__ float bsel(u64 mask, u64 lanebit, float v) {
    return (mask & lanebit) ? 0.0f : v;
}

// ---------------- streaming register-pipeline NMS (unchanged from r6) ----------------

__global__ __launch_bounds__(256, 4) void k_nms(const float* __restrict__ S_,
                                                u64* __restrict__ cand,
                                                u32* __restrict__ cnt) {
    __shared__ u64 lbuf[4][LBUFW];

    int lane = threadIdx.x & 63;
    int wslot = threadIdx.x >> 6;
    int sx = blockIdx.x * 4 + wslot;      // 0..23  (24*44 = 1056 >= 1024)
    int sy = blockIdx.y;                  // 0..15  (64-row strips)
    int img = blockIdx.z;
    int gx0 = sx * 44 - 10;
    int gy0 = sy * 64;
    int gx = gx0 + lane;
    bool lxok = (unsigned)gx < (unsigned)W;
    u64 lanebit = 1ull << lane;
    const float* Sb = S_ + ((size_t)img << 20);

    u64 validx = __ballot(lxok);
    u64 emask = __ballot(lane >= 10 && lane <= 53 && gx >= 2 && gx <= W - 3);

    float S[14], R0[8], R1[8], R2[8], nxt[4];
    u64 M0[8], M1[8], SP1[6], SP2[6];
#pragma unroll
    for (int k = 0; k < 14; ++k) S[k] = -1.0f;
#pragma unroll
    for (int k = 0; k < 8; ++k) { R0[k] = -1e30f; R1[k] = -1e30f; R2[k] = -1e30f; M0[k] = 0; M1[k] = 0; }
#pragma unroll
    for (int k = 0; k < 6; ++k) { SP1[k] = 0; SP2[k] = 0; }

    u32 wbase = 0;
    int y0 = gy0 - 10;

#pragma unroll
    for (int j = 0; j < 4; ++j) {
        int gy = y0 + j;
        nxt[j] = ((unsigned)gy < (unsigned)H && lxok) ? Sb[(gy << 10) + gx] : -1.0f;
    }

    for (int cy = 0; cy < 21; ++cy, y0 += 4) {
#pragma unroll
        for (int j = 0; j < 4; ++j) S[10 + j] = nxt[j];
        if (cy < 20) {
#pragma unroll
            for (int j = 0; j < 4; ++j) {
                int gy = y0 + 4 + j;
                nxt[j] = ((unsigned)gy < (unsigned)H && lxok) ? Sb[(gy << 10) + gx] : -1.0f;
            }
        }
#pragma unroll
        for (int j = 0; j < 4; ++j) {
            float fr = S[10 + j];
            float f_m1 = __shfl_up(fr, 1), f_m2 = __shfl_up(fr, 2);
            float f_p1 = __shfl_down(fr, 1), f_p2 = __shfl_down(fr, 2);
            float ar = S[j + 6];
            float a_m1 = __shfl_up(ar, 1), a_m2 = __shfl_up(ar, 2);
            float a_p1 = __shfl_down(ar, 1), a_p2 = __shfl_down(ar, 2);
            float br = S[j + 2];
            float b_m1 = __shfl_up(br, 1), b_m2 = __shfl_up(br, 2);
            float b_p1 = __shfl_down(br, 1), b_p2 = __shfl_down(br, 2);

            R0[4 + j] = max5(f_m2, f_m1, fr, f_p1, f_p2);
            float c0 = MAX5R(R0, j);
            u64 m0 = __ballot(S[j + 8] == c0) & validx;
            M0[4 + j] = m0;

            u64 sp1 = xdilate(OR5(M0, j));
            SP1[2 + j] = sp1;

            float h1 = max5(bsel(sp1 << 2, lanebit, a_m2), bsel(sp1 << 1, lanebit, a_m1),
                            bsel(sp1, lanebit, ar),
                            bsel(sp1 >> 1, lanebit, a_p1), bsel(sp1 >> 2, lanebit, a_p2));
            R1[4 + j] = h1;
            float c1 = MAX5R(R1, j);
            float ss1b = bsel(SP1[j], lanebit, S[j + 4]);
            u64 new1 = __ballot(ss1b == c1) & validx;
            u64 m1 = M0[j] | (new1 & ~SP1[j]);
            M1[4 + j] = m1;

            u64 sp2 = xdilate(OR5(M1, j));
            SP2[2 + j] = sp2;

            float h2 = max5(bsel(sp2 << 2, lanebit, b_m2), bsel(sp2 << 1, lanebit, b_m1),
                            bsel(sp2, lanebit, br),
                            bsel(sp2 >> 1, lanebit, b_p1), bsel(sp2 >> 2, lanebit, b_p2));
            R2[4 + j] = h2;

            if (cy >= 5) {
                float c2 = MAX5R(R2, j);
                float ss2b = bsel(SP2[j], lanebit, S[j]);
                u64 new2 = __ballot(ss2b == c2) & validx;
                u64 m2 = M1[j] | (new2 & ~SP2[j]);
                int gy_out = y0 + j - 10;
                if (gy_out >= 2 && gy_out <= H - 3) {
                    float val = (m2 & lanebit) ? S[j] : 0.0f;
                    u64 bm = __ballot(val > 0.0f) & emask;
                    if (bm) {
                        u32 cw = (u32)__popcll(bm);
                        u32 prefix = (u32)__popcll(bm & (lanebit - 1ull));
                        if ((bm & lanebit) && (wbase + prefix) < LBUFW) {
                            u64 key = (((u64)__float_as_uint(val)) << 32) |
                                      (u32)(~(u32)((gy_out << 10) + gx));
                            lbuf[wslot][wbase + prefix] = key;
                        }
                        wbase += cw;
                    }
                }
            }
        }
#pragma unroll
        for (int k = 0; k < 10; ++k) S[k] = S[k + 4];
#pragma unroll
        for (int k = 0; k < 4; ++k) {
            R0[k] = R0[k + 4]; R1[k] = R1[k + 4]; R2[k] = R2[k + 4];
            M0[k] = M0[k + 4]; M1[k] = M1[k + 4];
        }
#pragma unroll
        for (int k = 0; k < 2; ++k) { SP1[k] = SP1[k + 4]; SP2[k] = SP2[k + 4]; }
    }

    u32 total = wbase > LBUFW ? LBUFW : wbase;
    u32 gbase = 0;
    if (lane == 0) gbase = atomicAdd(&cnt[img * CSTR], total);
    gbase = (u32)__shfl((int)gbase, 0, 64);
    u64* dst = cand + ((size_t)img << 17);
    for (u32 i = lane; i < total; i += 64)
        dst[gbase + i] = lbuf[wslot][i];
}

// ---- fused: LDS histogram + desc prefix + threshold + counting-sort scatter ----
// 1 block / image. gath comes out bucket-ordered (descending buckets);
// dparr[img][b] = #keys in buckets > b (segment starts for rankfinal).

__global__ __launch_bounds__(1024) void k_select(const u64* __restrict__ cand,
                                                 const u32* __restrict__ cnt,
                                                 u64* __restrict__ gath,
                                                 u32* __restrict__ gcnt,
                                                 u32* __restrict__ dparr) {
    __shared__ u32 h0[8193];
    __shared__ u32 h1[8193];
    __shared__ u32 wpart[16], woff[16];
    __shared__ u32 sBstar, sgcnt, sTotAll;
    int img = blockIdx.x;
    int t = threadIdx.x;
    int lane = t & 63, wid = t >> 6;

    for (int i = t; i < 8193; i += 1024) { h0[i] = 0; h1[i] = 0; }
    __syncthreads();

    u32 n = cnt[img * CSTR];
    if (n > CANDCAP) n = CANDCAP;
    const u64* c = cand + ((size_t)img << 17);
    u32* hs = (t & 1) ? h1 : h0;            // 2 shards halve same-address serialization
    for (u32 i = t; i < n; i += 1024)
        atomicAdd(&hs[val_bucket((u32)(c[i] >> 32))], 1u);
    __syncthreads();

    // thread t owns buckets hi..hi-7 (descending); covers 8192..1
    int hi = 8192 - 8 * t;
    u32 loc[8];
    u32 psum = 0;
#pragma unroll
    for (int i = 0; i < 8; ++i) { loc[i] = h0[hi - i] + h1[hi - i]; psum += loc[i]; }
    u32 c0 = 0;
    if (t == 1023) c0 = h0[0] + h1[0];

    // wave-inclusive scan, then block offsets
    u32 incl = psum;
#pragma unroll
    for (int d = 1; d < 64; d <<= 1) {
        u32 v = (u32)__shfl_up((int)incl, d);
        if (lane >= d) incl += v;
    }
    if (lane == 63) wpart[wid] = incl;
    __syncthreads();
    if (t == 0) {
        u32 acc = 0;
        for (int w2 = 0; w2 < 16; ++w2) { woff[w2] = acc; acc += wpart[w2]; }
    }
    __syncthreads();
    u32 total1 = woff[15] + wpart[15];           // keys in buckets >= 1
    u32 excl = incl - psum + woff[wid];          // keys in buckets > hi

    u32* dpi = dparr + (u32)img * 8193;
    u32 dpv = excl;
#pragma unroll
    for (int i = 0; i < 8; ++i) {
        h1[hi - i] = dpv;                        // scatter offset counter init
        dpi[hi - i] = dpv;                       // global segment starts
        dpv += loc[i];
    }
    if (t == 1023) {                             // bucket 0: dp = total1
        h1[0] = dpv;
        dpi[0] = dpv;
        sTotAll = total1 + c0;
    }
    if (excl < TOPK && excl + psum >= TOPK) {
        u32 cum = excl;
#pragma unroll
        for (int i = 0; i < 8; ++i) {
            cum += loc[i];
            if (cum >= TOPK) { sBstar = (u32)(hi - i); sgcnt = cum; break; }
        }
    }
    __syncthreads();
    if (t == 0 && total1 < TOPK) {               // degenerate fallback (never on this data)
        sBstar = 0;
        sgcnt = sTotAll > GCAP ? GCAP : sTotAll;
    }
    __syncthreads();

    u32 Bs = sBstar;
    u64* g = gath + ((size_t)img << 13);
    for (u32 i = t; i < n; i += 1024) {
        u64 key = c[i];
        u32 b = val_bucket((u32)(key >> 32));
        if (b >= Bs) {
            u32 pos = atomicAdd(&h1[b], 1u);
            if (pos < GCAP) g[pos] = key;
        }
    }
    if (t == 0) gcnt[img * CSTR] = sgcnt > GCAP ? GCAP : sgcnt;
}

// ---- fused: exact rank (bucket-segment scan) + softmax patch + dispersity + bilinear ----

__global__ __launch_bounds__(1024) void k_rankfinal(const u64* __restrict__ gath,
                                                    const u32* __restrict__ gcnt,
                                                    const u32* __restrict__ dparr,
                                                    const float* __restrict__ S,
                                                    float* __restrict__ out) {
    int img = blockIdx.y;
    u32 n = gcnt[img * CSTR];
    u32 i = blockIdx.x * 1024 + threadIdx.x;
    if (i >= n) return;
    const u64* g = gath + ((size_t)img << 13);
    u64 key = g[i];
    u32 b = val_bucket((u32)(key >> 32));
    const u32* dpi = dparr + (u32)img * 8193;
    u32 lo = dpi[b];
    u32 hiE = (b >= 1) ? dpi[b - 1] : n;
    if (hiE > n) hiE = n;
    u32 r = lo;
    for (u32 j = lo; j < hiE; ++j) r += (g[j] > key);
    if (r >= TOPK) return;

    u32 rem = ~(u32)(key & 0xFFFFFFFFull);
    int row = (int)(rem >> 10);
    int col = (int)(rem & (W - 1));
    const float* Sb = S + ((size_t)img << 20);

    float p[25];
    float mx = -1e30f;
#pragma unroll
    for (int a2 = 0; a2 < 5; ++a2) {
        int y = row + a2 - 2;
#pragma unroll
        for (int c2 = 0; c2 < 5; ++c2) {
            int x = col + c2 - 2;
            float v = (y >= 0 && y < H && x >= 0 && x < W) ? Sb[(y << 10) + x] : 0.0f;
            p[a2 * 5 + c2] = v;
            mx = fmaxf(mx, v);
        }
    }
    float sum = 0.0f, sx = 0.0f, sy = 0.0f;
#pragma unroll
    for (int a2 = 0; a2 < 5; ++a2) {
#pragma unroll
        for (int c2 = 0; c2 < 5; ++c2) {
            float e = expf((p[a2 * 5 + c2] - mx) / 0.1f);
            p[a2 * 5 + c2] = e;
            sum += e;
            sx += e * (float)(c2 - 2);
            sy += e * (float)(a2 - 2);
        }
    }
    float rx = sx / sum, ry = sy / sum;
    float sd = 0.0f;
#pragma unroll
    for (int a2 = 0; a2 < 5; ++a2) {
#pragma unroll
        for (int c2 = 0; c2 < 5; ++c2) {
            float dxx = ((float)(c2 - 2) - rx) * 0.5f;
            float dyy = ((float)(a2 - 2) - ry) * 0.5f;
            sd += p[a2 * 5 + c2] * (dxx * dxx + dyy * dyy);
        }
    }
    float disp = sd / sum;
    float kx = ((float)col + rx) / (float)(W - 1) * 2.0f - 1.0f;
    float ky = ((float)row + ry) / (float)(H - 1) * 2.0f - 1.0f;

    float px = (kx + 1.0f) * 0.5f * (float)(W - 1);
    float py = (ky + 1.0f) * 0.5f * (float)(H - 1);
    float x0 = floorf(px), y0 = floorf(py);
    float wx1 = px - x0, wx0 = 1.0f - wx1;
    float wy1 = py - y0, wy0 = 1.0f - wy1;

    float gg[4];
    float xs[4] = {x0, x0 + 1.0f, x0, x0 + 1.0f};
    float ys[4] = {y0, y0, y0 + 1.0f, y0 + 1.0f};
#pragma unroll
    for (int q = 0; q < 4; ++q) {
        int xi = (int)xs[q]; xi = xi < 0 ? 0 : (xi > W - 1 ? W - 1 : xi);
        int yi = (int)ys[q]; yi = yi < 0 ? 0 : (yi > H - 1 ? H - 1 : yi);
        bool valid = (xs[q] >= 0.0f) && (xs[q] <= (float)(W - 1)) &&
                     (ys[q] >= 0.0f) && (ys[q] <= (float)(H - 1));
        gg[q] = valid ? Sb[(yi << 10) + xi] : 0.0f;
    }
    float score = wy0 * wx0 * gg[0] + wy0 * wx1 * gg[1] + wy1 * wx0 * gg[2] + wy1 * wx1 * gg[3];

    u32 slot = ((u32)img << 12) + r;
    out[(size_t)slot * 2]     = kx;
    out[(size_t)slot * 2 + 1] = ky;
    out[B * TOPK * 2 + slot]            = disp;
    out[B * TOPK * 2 + B * TOPK + slot] = score;
}

// ---------------- launch ----------------

extern "C" void kernel_launch(void* const* d_in, const int* in_sizes, int n_in,
                              void* d_out, int out_size, void* d_ws, size_t ws_size,
                              hipStream_t stream) {
    const float* S = (const float*)d_in[0];
    float* out = (float*)d_out;

    char* w = (char*)d_ws;
    u64* cand = (u64*)w;        w += (size_t)B * CANDCAP * 8;
    u64* gath = (u64*)w;        w += (size_t)B * GCAP * 8;
    u32* dparr = (u32*)w;       w += (size_t)B * 8193 * 4;
    u32* cnt = (u32*)w;         w += B * CSTR * 4;
    u32* gcnt = (u32*)w;        w += B * CSTR * 4;

    // zero cnt + gcnt (contiguous, 2 KB)
    hipMemsetAsync(cnt, 0, 2 * B * CSTR * 4, stream);

    k_nms<<<dim3(6, 16, B), 256, 0, stream>>>(S, cand, cnt);
    k_select<<<B, 1024, 0, stream>>>(cand, cnt, gath, gcnt, dparr);
    k_rankfinal<<<dim3(8, B), 1024, 0, stream>>>(gath, gcnt, dparr, S, out);
}